// Round 4
// baseline (277.360 us; speedup 1.0000x reference)
//
#include <hip/hip_runtime.h>

#define B_   32
#define L_   512
#define D_   384
#define M_   (B_*L_)    // 16384 rows
#define KTOT (D_*3)     // 1152 GEMM K
#define LDW  392        // LDS row stride in bf16 elems (784B: 16B-aligned, 2-way bank alias)
#define BROWS 82        // 80 data rows + 2 guard rows (64 out + 8/8 halo + edges)
#define BUFE (BROWS*LDW)
#define CHUNKE 12288    // bf16 elems per 24 KB weight K-chunk

typedef __bf16 bf16x8 __attribute__((ext_vector_type(8)));
typedef float  floatx4 __attribute__((ext_vector_type(4)));

// ---------------- weight repack: chunk-major fragment layout (unchanged) ----------
// W3[((c*24 + t)*64 + lane)*8 + j] = w[o = t*16 + (lane&15)][kflat = c*32 + (lane>>4)*8 + j]
// kflat = s*384 + i.  Chunk c = s*12 + it is a contiguous 24576 B block.
__global__ __launch_bounds__(256) void repack4_kernel(const float* __restrict__ wa,
                                                      const float* __restrict__ wb,
                                                      const float* __restrict__ wc,
                                                      const float* __restrict__ wd,
                                                      __bf16* __restrict__ oa,
                                                      __bf16* __restrict__ ob,
                                                      __bf16* __restrict__ oc,
                                                      __bf16* __restrict__ od)
{
    int idx = blockIdx.x * 256 + threadIdx.x;
    if (idx >= D_ * KTOT) return;
    const float* w; __bf16* o_;
    switch (blockIdx.y) {
        case 0:  w = wa; o_ = oa; break;
        case 1:  w = wb; o_ = ob; break;
        case 2:  w = wc; o_ = oc; break;
        default: w = wd; o_ = od; break;
    }
    int j  = idx & 7;
    int l  = (idx >> 3) & 63;
    int ct = idx >> 9;          // c*24 + t
    int c  = ct / 24;
    int t  = ct - c * 24;
    int o  = t * 16 + (l & 15);
    int kflat = c * 32 + (l >> 4) * 8 + j;
    int s  = kflat / D_;
    int i  = kflat - s * D_;
    o_[idx] = (__bf16)w[(o * D_ + i) * 3 + s];
}

// ---------------- fused DurationPredictor: 4 convs + 2 LN + head, ONE kernel ------
// r11: 256 blocks x 64 rows x 512 threads (8 waves), 1M x 8N decomposition
// (wave w owns cols [w*48,w*48+48), all 5 m-tiles). B weights now flow
// global -> regs -> LDS chunk buffers (T14 split: loads issued at step top,
// ds_write after MFMA) with a 3-buffer rotation and ONE barrier per K-step
// (T3 minimal pipeline). This removes the per-wave global->MFMA latency chain
// that made the old loop latency-bound at 2 waves/SIMD.
// Data buffer is a SINGLE in-place 82-row LDS tile (validated in r10): stage
// epilogues overwrite rows 1..80; guard rows 0/81 keep stale x (finite),
// used only by halo rows that die before the needed region [9,72].
// Valid rows: x [0,81] -> st0 [1,80] -> st1 [2,79] -> st2 [3,78] -> st3 [4,77].
__global__ __launch_bounds__(512, 1) void fused_predictor(
    const float* __restrict__ x,
    const __bf16* __restrict__ w1a, const float* __restrict__ b1a,
    const __bf16* __restrict__ w1b, const float* __restrict__ b1b,
    const float* __restrict__ g1,  const float* __restrict__ e1,
    const __bf16* __restrict__ w2a, const float* __restrict__ b2a,
    const __bf16* __restrict__ w2b, const float* __restrict__ b2b,
    const float* __restrict__ g2,  const float* __restrict__ e2,
    const float* __restrict__ lw,  const float* __restrict__ lb,
    float* __restrict__ out_dur)
{
    extern __shared__ char smem_raw[];
    __bf16* buf  = (__bf16*)smem_raw;        // [BROWS][LDW] data tile (in place)
    __bf16* cbs  = buf + BUFE;               // 3 x CHUNKE weight chunk buffers
    float*  red1 = (float*)(cbs + 3 * CHUNKE);   // [BROWS][8]
    float*  red2 = red1 + BROWS * 8;             // [BROWS][8]
    float*  minv = red2 + BROWS * 8;             // [BROWS][2]

    const int m0 = blockIdx.x * 64;
    const int l0 = m0 & 511;
    const int b0 = m0 - l0;

    const int tid  = threadIdx.x;
    const int wave = tid >> 6;        // 0..7 = N-group; cols [wave*48, wave*48+48)
    const int lane = tid & 63;
    const int quad = lane >> 4;
    const int lx   = lane & 15;

    bf16x8 kz;
#pragma unroll
    for (int z = 0; z < 8; z++) kz[z] = (__bf16)0.f;

    // ---- stage x -> buf rows 0..81 (fp32->bf16, zero outside seq) ----
    for (int c = tid; c < BROWS * 48; c += 512) {
        int beta = c / 48, q = c - beta * 48;
        int l = l0 + beta - 9;
        bf16x8 v = kz;
        if ((unsigned)l < (unsigned)L_) {
            const float* xr = x + (size_t)(b0 + l) * D_ + q * 8;
            const float4 f0 = *(const float4*)xr;
            const float4 f1 = *(const float4*)(xr + 4);
            v[0] = (__bf16)f0.x; v[1] = (__bf16)f0.y; v[2] = (__bf16)f0.z; v[3] = (__bf16)f0.w;
            v[4] = (__bf16)f1.x; v[5] = (__bf16)f1.y; v[6] = (__bf16)f1.z; v[7] = (__bf16)f1.w;
        }
        *(bf16x8*)(&buf[beta * LDW + q * 8]) = v;
    }
    // (no barrier here: the stage-0 prologue barrier below covers it)

    const int t0   = wave * 3;                // first n-tile of this wave
    const int col0 = wave * 48 + lx;          // col for ni: col0 + ni*16

    floatx4 acc[5][3];

    for (int st = 0; st < 4; st++) {
        const __bf16* Wp = (st == 0) ? w1a : (st == 1) ? w1b : (st == 2) ? w2a : w2b;
        const float*  bp = (st == 0) ? b1a : (st == 1) ? b1b : (st == 2) ? b2a : b2b;

#pragma unroll
        for (int mt = 0; mt < 5; mt++)
#pragma unroll
            for (int ni = 0; ni < 3; ni++)
#pragma unroll
                for (int r = 0; r < 4; r++) acc[mt][ni][r] = 0.f;

        // ---- chunk prologue: stage c(n=0)=0 -> cb0, c(n=1)=12 -> cb1 ----
        {
            const bf16x8* s0 = (const bf16x8*)Wp + tid;                       // chunk 0
            const bf16x8* s1 = (const bf16x8*)(Wp + 12 * CHUNKE) + tid;       // chunk 12
            bf16x8 a0 = s0[0], a1 = s0[512], a2 = s0[1024];
            bf16x8 c0 = s1[0], c1 = s1[512], c2v = s1[1024];
            bf16x8* d0 = (bf16x8*)cbs + tid;
            bf16x8* d1 = (bf16x8*)(cbs + CHUNKE) + tid;
            d0[0] = a0; d0[512] = a1; d0[1024] = a2;
            d1[0] = c0; d1[512] = c1; d1[1024] = c2v;
        }
        __syncthreads();   // buf writes (x-stage / prev epilogue) + chunks 0,1 visible

        const __bf16* ab = buf + lx * LDW + quad * 8;
#pragma unroll
        for (int n = 0; n < 36; n++) {
            const int it = n / 3, s = n - it * 3;
            // T14 issue-early: global loads for chunk(n+2)
            bf16x8 sg0, sg1, sg2;
            const bool do_stage = (n + 2 < 36);
            if (do_stage) {
                const int c2 = ((n + 2) % 3) * 12 + (n + 2) / 3;   // chunk id of step n+2
                const bf16x8* src = (const bf16x8*)(Wp + (size_t)c2 * CHUNKE) + tid;
                sg0 = src[0]; sg1 = src[512]; sg2 = src[1024];
            }
            // B frags from LDS chunk buffer (n%3)
            const __bf16* cbn = cbs + (n % 3) * CHUNKE;
            bf16x8 bfr[3];
#pragma unroll
            for (int ni = 0; ni < 3; ni++)
                bfr[ni] = *(const bf16x8*)(cbn + (t0 + ni) * 512 + lane * 8);
            // A frags from data buffer
            bf16x8 af[5];
#pragma unroll
            for (int mt = 0; mt < 5; mt++)
                af[mt] = *(const bf16x8*)(ab + (mt * 16 + s) * LDW + it * 32);
            __builtin_amdgcn_s_setprio(1);
#pragma unroll
            for (int mt = 0; mt < 5; mt++)
#pragma unroll
                for (int ni = 0; ni < 3; ni++)
                    acc[mt][ni] = __builtin_amdgcn_mfma_f32_16x16x32_bf16(af[mt], bfr[ni], acc[mt][ni], 0, 0, 0);
            __builtin_amdgcn_s_setprio(0);
            // T14 write-late: chunk(n+2) -> buffer (n+2)%3 (freed at step n-1's barrier)
            if (do_stage) {
                bf16x8* d = (bf16x8*)(cbs + ((n + 2) % 3) * CHUNKE) + tid;
                d[0] = sg0; d[512] = sg1; d[1024] = sg2;
            }
            __syncthreads();
        }

        // ---- epilogue: bias + relu (in regs) ----
        float bv[3];
#pragma unroll
        for (int ni = 0; ni < 3; ni++) bv[ni] = bp[col0 + ni * 16];
#pragma unroll
        for (int mt = 0; mt < 5; mt++)
#pragma unroll
            for (int ni = 0; ni < 3; ni++)
#pragma unroll
                for (int r = 0; r < 4; r++) {
                    float vv = acc[mt][ni][r] + bv[ni];
                    acc[mt][ni][r] = vv > 0.f ? vv : 0.f;
                }

        if (st == 1 || st == 3) {
            // ---- LayerNorm: row stats via lx-shuffle + cross-wave LDS reduce ----
#pragma unroll
            for (int mt = 0; mt < 5; mt++)
#pragma unroll
                for (int r = 0; r < 4; r++) {
                    float s1 = acc[mt][0][r] + acc[mt][1][r] + acc[mt][2][r];
                    float s2 = acc[mt][0][r] * acc[mt][0][r] + acc[mt][1][r] * acc[mt][1][r]
                             + acc[mt][2][r] * acc[mt][2][r];
#pragma unroll
                    for (int d = 1; d < 16; d <<= 1) {
                        s1 += __shfl_xor(s1, d);
                        s2 += __shfl_xor(s2, d);
                    }
                    if (lx == 0) {
                        int beta = mt * 16 + quad * 4 + r + 1;
                        red1[beta * 8 + wave] = s1;
                        red2[beta * 8 + wave] = s2;
                    }
                }
            __syncthreads();
            if (tid < BROWS) {
                float s1 = 0.f, s2 = 0.f;
#pragma unroll
                for (int k = 0; k < 8; k++) { s1 += red1[tid * 8 + k]; s2 += red2[tid * 8 + k]; }
                float mean = s1 * (1.f / D_);
                float var  = s2 * (1.f / D_) - mean * mean;
                minv[tid * 2]     = mean;
                minv[tid * 2 + 1] = rsqrtf(var + 1e-5f);
            }
            __syncthreads();
            const float* gp = (st == 1) ? g1 : g2;
            const float* ep = (st == 1) ? e1 : e2;
            float gv[3], ev[3];
#pragma unroll
            for (int ni = 0; ni < 3; ni++) { gv[ni] = gp[col0 + ni * 16]; ev[ni] = ep[col0 + ni * 16]; }
#pragma unroll
            for (int mt = 0; mt < 5; mt++)
#pragma unroll
                for (int r = 0; r < 4; r++) {
                    int beta = mt * 16 + quad * 4 + r + 1;
                    float mean = minv[beta * 2], inv = minv[beta * 2 + 1];
#pragma unroll
                    for (int ni = 0; ni < 3; ni++)
                        acc[mt][ni][r] = (acc[mt][ni][r] - mean) * inv * gv[ni] + ev[ni];
                }
            if (st == 1) {
#pragma unroll
                for (int mt = 0; mt < 5; mt++)
#pragma unroll
                    for (int r = 0; r < 4; r++) {
                        int beta = mt * 16 + quad * 4 + r + 1;
                        bool ok = (unsigned)(l0 + beta - 9) < (unsigned)L_;
#pragma unroll
                        for (int ni = 0; ni < 3; ni++)
                            buf[beta * LDW + col0 + ni * 16] = (__bf16)(ok ? acc[mt][ni][r] : 0.f);
                    }
            } else {
                // ---- head: dot with lin_w, cross-wave reduce, store dur_preds ----
                float lwv[3];
#pragma unroll
                for (int ni = 0; ni < 3; ni++) lwv[ni] = lw[col0 + ni * 16];
#pragma unroll
                for (int mt = 0; mt < 5; mt++)
#pragma unroll
                    for (int r = 0; r < 4; r++) {
                        float p = acc[mt][0][r] * lwv[0] + acc[mt][1][r] * lwv[1] + acc[mt][2][r] * lwv[2];
#pragma unroll
                        for (int d = 1; d < 16; d <<= 1) p += __shfl_xor(p, d);
                        if (lx == 0) {
                            int beta = mt * 16 + quad * 4 + r + 1;
                            red1[beta * 8 + wave] = p;
                        }
                    }
                __syncthreads();
                if (tid < 64) {
                    int beta = tid + 9;
                    float sacc = lb[0];
#pragma unroll
                    for (int k = 0; k < 8; k++) sacc += red1[beta * 8 + k];
                    out_dur[m0 + tid] = sacc;
                }
            }
        } else {
            // ---- plain write (conv1a / conv2a outputs), in place ----
            // last K-step barrier already guarantees all reads of buf are done
#pragma unroll
            for (int mt = 0; mt < 5; mt++)
#pragma unroll
                for (int r = 0; r < 4; r++) {
                    int beta = mt * 16 + quad * 4 + r + 1;
                    bool ok = (unsigned)(l0 + beta - 9) < (unsigned)L_;
#pragma unroll
                    for (int ni = 0; ni < 3; ni++)
                        buf[beta * LDW + col0 + ni * 16] = (__bf16)(ok ? acc[mt][ni][r] : 0.f);
                }
        }
        // next stage's prologue barrier orders these writes before any read
    }
}

// ---------------- cumsum of durations, wave per batch ----------------
__global__ __launch_bounds__(64) void cum_kernel(const int* __restrict__ dur,
                                                 int* __restrict__ cum)
{
    int b = blockIdx.x, lane = threadIdx.x;
    const int* db = dur + b * L_;
    int v[8], s = 0;
#pragma unroll
    for (int i = 0; i < 8; i++) { v[i] = db[lane * 8 + i]; s += v[i]; }
    int ex = s;
#pragma unroll
    for (int off = 1; off < 64; off <<= 1) {
        int n = __shfl_up(ex, off);
        if (lane >= off) ex += n;
    }
    ex -= s;
    int c = ex;
    int* cb = cum + b * L_;
#pragma unroll
    for (int i = 0; i < 8; i++) { c += v[i]; cb[lane * 8 + i] = c; }
}

// ---------------- gather / length-regulate, block per frame (proven best) --------
__global__ __launch_bounds__(128) void gather_kernel(const float* __restrict__ x,
                                                     const int* __restrict__ cum,
                                                     float* __restrict__ out, int T)
{
    int fr = blockIdx.x;
    int b  = fr / T;
    int t  = fr - b * T;
    int tid = threadIdx.x;
    const int* cb = cum + b * L_;
    int total = cb[L_ - 1];
    float4 val = make_float4(0.f, 0.f, 0.f, 0.f);
    if (t < total) {
        int lo = 0, hi = L_;
        while (lo < hi) { int mid = (lo + hi) >> 1; if (cb[mid] > t) hi = mid; else lo = mid + 1; }
        if (tid < 96) val = *(const float4*)(x + ((size_t)(b * L_ + lo)) * D_ + tid * 4);
    }
    if (tid < 96) *(float4*)(out + (size_t)fr * D_ + tid * 4) = val;
}

extern "C" void kernel_launch(void* const* d_in, const int* in_sizes, int n_in,
                              void* d_out, int out_size, void* d_ws, size_t ws_size,
                              hipStream_t stream) {
    const float* x       = (const float*)d_in[0];
    const int*   dur     = (const int*)d_in[1];
    const float* c1a_w   = (const float*)d_in[2];
    const float* c1a_b   = (const float*)d_in[3];
    const float* c1b_w   = (const float*)d_in[4];
    const float* c1b_b   = (const float*)d_in[5];
    const float* ln1_g   = (const float*)d_in[6];
    const float* ln1_b   = (const float*)d_in[7];
    const float* c2a_w   = (const float*)d_in[8];
    const float* c2a_b   = (const float*)d_in[9];
    const float* c2b_w   = (const float*)d_in[10];
    const float* c2b_b   = (const float*)d_in[11];
    const float* ln2_g   = (const float*)d_in[12];
    const float* ln2_b   = (const float*)d_in[13];
    const float* lin_w   = (const float*)d_in[14];
    const float* lin_b   = (const float*)d_in[15];

    const int T = (out_size - B_ * L_) / (B_ * D_);
    float* out_gather = (float*)d_out;
    float* out_dur    = (float*)d_out + (size_t)B_ * T * D_;

    // workspace: 4 repacked weights + cumsum
    char* p = (char*)d_ws;
    __bf16* w1a = (__bf16*)p; p += (size_t)D_ * KTOT * 2;
    __bf16* w1b = (__bf16*)p; p += (size_t)D_ * KTOT * 2;
    __bf16* w2a = (__bf16*)p; p += (size_t)D_ * KTOT * 2;
    __bf16* w2b = (__bf16*)p; p += (size_t)D_ * KTOT * 2;
    int* cum = (int*)p; p += (size_t)B_ * L_ * 4;

    // LR path (independent of predictor chain)
    cum_kernel<<<B_, 64, 0, stream>>>(dur, cum);
    gather_kernel<<<B_ * T, 128, 0, stream>>>(x, cum, out_gather, T);

    // predictor chain: repack -> one fused kernel
    dim3 rpgrid((D_ * KTOT + 255) / 256, 4);
    repack4_kernel<<<rpgrid, 256, 0, stream>>>(c1a_w, c1b_w, c2a_w, c2b_w, w1a, w1b, w2a, w2b);

    const size_t smem = (size_t)BUFE * 2 + 3 * 24576 + (BROWS * 8 * 2 + BROWS * 2) * 4;  // 143920 B
    static bool attr_set = false;
    if (!attr_set) {
        hipFuncSetAttribute((const void*)fused_predictor,
                            hipFuncAttributeMaxDynamicSharedMemorySize, (int)smem);
        attr_set = true;
    }
    fused_predictor<<<M_ / 64, 512, smem, stream>>>(
        x, w1a, c1a_b, w1b, c1b_b, ln1_g, ln1_b,
        w2a, c2a_b, w2b, c2b_b, ln2_g, ln2_b,
        lin_w, lin_b, out_dur);
}

// Round 5
// 249.728 us; speedup vs baseline: 1.1107x; 1.1107x over previous
//
#include <hip/hip_runtime.h>

#define B_   32
#define L_   512
#define D_   384
#define M_   (B_*L_)    // 16384 rows
#define KTOT (D_*3)     // 1152 GEMM K
#define LDW  392        // LDS row stride in bf16 elems (784B: 16B-aligned, 2-way bank alias)
#define BROWS 82        // 80 data rows + 2 guard rows
#define BUFE (BROWS*LDW)

typedef __bf16 bf16x8 __attribute__((ext_vector_type(8)));
typedef float  floatx4 __attribute__((ext_vector_type(4)));

// ---------------- weight repack: chunk-major fragment layout (unchanged) ----------
// W3[((c*24 + t)*64 + lane)*8 + j] = w[o = t*16 + (lane&15)][kflat = c*32 + (lane>>4)*8 + j]
// kflat = s*384 + i.
__global__ __launch_bounds__(256) void repack4_kernel(const float* __restrict__ wa,
                                                      const float* __restrict__ wb,
                                                      const float* __restrict__ wc,
                                                      const float* __restrict__ wd,
                                                      __bf16* __restrict__ oa,
                                                      __bf16* __restrict__ ob,
                                                      __bf16* __restrict__ oc,
                                                      __bf16* __restrict__ od)
{
    int idx = blockIdx.x * 256 + threadIdx.x;
    if (idx >= D_ * KTOT) return;
    const float* w; __bf16* o_;
    switch (blockIdx.y) {
        case 0:  w = wa; o_ = oa; break;
        case 1:  w = wb; o_ = ob; break;
        case 2:  w = wc; o_ = oc; break;
        default: w = wd; o_ = od; break;
    }
    int j  = idx & 7;
    int l  = (idx >> 3) & 63;
    int ct = idx >> 9;          // c*24 + t
    int c  = ct / 24;
    int t  = ct - c * 24;
    int o  = t * 16 + (l & 15);
    int kflat = c * 32 + (l >> 4) * 8 + j;
    int s  = kflat / D_;
    int i  = kflat - s * D_;
    o_[idx] = (__bf16)w[(o * D_ + i) * 3 + s];
}

// ---------------- fused DurationPredictor (r8-proven: 88.9 us, VGPR 116) ----------
// 512 threads (8 waves) own 64 output rows. 2M x 4N wave decomposition:
// ng = wave&3 owns cols [ng*96, ng*96+96) (6 n-tiles); mg = wave>>2 owns
// m-tiles {0,1,2} or {3,4}. Wave pair (w, w+4) shares ng on the same SIMD.
__global__ __launch_bounds__(512, 1) void fused_predictor(
    const float* __restrict__ x,
    const __bf16* __restrict__ w1a, const float* __restrict__ b1a,
    const __bf16* __restrict__ w1b, const float* __restrict__ b1b,
    const float* __restrict__ g1,  const float* __restrict__ e1,
    const __bf16* __restrict__ w2a, const float* __restrict__ b2a,
    const __bf16* __restrict__ w2b, const float* __restrict__ b2b,
    const float* __restrict__ g2,  const float* __restrict__ e2,
    const float* __restrict__ lw,  const float* __restrict__ lb,
    float* __restrict__ out_dur)
{
    extern __shared__ char smem_raw[];
    __bf16* bufA = (__bf16*)smem_raw;
    __bf16* bufB = bufA + BUFE;
    float*  red1 = (float*)(bufB + BUFE);    // [BROWS][8]
    float*  red2 = red1 + BROWS * 8;         // [BROWS][8]
    float*  minv = red2 + BROWS * 8;         // [BROWS][2]

    const int m0 = blockIdx.x * 64;
    const int l0 = m0 & 511;
    const int b0 = m0 - l0;

    const int tid  = threadIdx.x;
    const int wave = tid >> 6;        // 0..7
    const int lane = tid & 63;
    const int quad = lane >> 4;
    const int lx   = lane & 15;
    const int ng   = wave & 3;        // N-group: cols [ng*96, ng*96+96)
    const int mg   = wave >> 2;       // M-group: 0 -> m-tiles 0..2, 1 -> 3..4
    const int mtc  = mg ? 2 : 3;      // tiles this wave computes
    const int mtb  = mg ? 3 : 0;      // first tile index

    bf16x8 kz;
#pragma unroll
    for (int z = 0; z < 8; z++) kz[z] = (__bf16)0.f;

    // ---- stage x -> bufA (fp32->bf16, zero outside seq); zero bufB guards ----
    for (int c = tid; c < BROWS * 48; c += 512) {
        int beta = c / 48, q = c - beta * 48;
        int l = l0 + beta - 9;
        bf16x8 v = kz;
        if ((unsigned)l < (unsigned)L_) {
            const float* xr = x + (size_t)(b0 + l) * D_ + q * 8;
            const float4 f0 = *(const float4*)xr;
            const float4 f1 = *(const float4*)(xr + 4);
            v[0] = (__bf16)f0.x; v[1] = (__bf16)f0.y; v[2] = (__bf16)f0.z; v[3] = (__bf16)f0.w;
            v[4] = (__bf16)f1.x; v[5] = (__bf16)f1.y; v[6] = (__bf16)f1.z; v[7] = (__bf16)f1.w;
        }
        *(bf16x8*)(&bufA[beta * LDW + q * 8]) = v;
    }
    for (int c = tid; c < 2 * 48; c += 512) {
        int beta = (c < 48) ? 0 : 81, q = c % 48;
        *(bf16x8*)(&bufB[beta * LDW + q * 8]) = kz;
    }
    __syncthreads();

    const int t0   = ng * 6;                  // first n-tile of this wave
    const int col0 = ng * 96 + lx;            // col for ni: col0 + ni*16

    floatx4 acc[3][6];
    bf16x8  bg[3][6];

    for (int st = 0; st < 4; st++) {
        const __bf16* bin  = (st & 1) ? bufB : bufA;
        __bf16*       bout = (st & 1) ? bufA : bufB;
        const __bf16* Wp = (st == 0) ? w1a : (st == 1) ? w1b : (st == 2) ? w2a : w2b;
        const float*  bp = (st == 0) ? b1a : (st == 1) ? b1b : (st == 2) ? b2a : b2b;

#pragma unroll
        for (int mt = 0; mt < 3; mt++)
            if (mt < mtc)
#pragma unroll
                for (int ni = 0; ni < 6; ni++)
#pragma unroll
                    for (int r = 0; r < 4; r++) acc[mt][ni][r] = 0.f;

        const char* pb0 = (const char*)Wp + ((size_t)t0 * 64 + lane) * 16;
        auto loadB = [&](int buf, int n) {
            int it = n / 3, s = n - it * 3;
            const char* p = pb0 + (size_t)(s * 12 + it) * 24576;
#pragma unroll
            for (int ni = 0; ni < 6; ni++)
                bg[buf][ni] = *(const bf16x8*)(p + ni * 1024);
        };
        loadB(0, 0); loadB(1, 1);

        const __bf16* ab = bin + (mtb * 16 + lx) * LDW + quad * 8;
#pragma unroll
        for (int n = 0; n < 36; n++) {
            const int it = n / 3, s = n - it * 3;
            if (n + 2 < 36) loadB((n + 2) % 3, n + 2);
            bf16x8 af[3];
            af[0] = *(const bf16x8*)(ab + (s) * LDW + it * 32);
            af[1] = *(const bf16x8*)(ab + (16 + s) * LDW + it * 32);
            if (mtc == 3)
                af[2] = *(const bf16x8*)(ab + (32 + s) * LDW + it * 32);
            __builtin_amdgcn_s_setprio(1);
#pragma unroll
            for (int ni = 0; ni < 6; ni++) {
                acc[0][ni] = __builtin_amdgcn_mfma_f32_16x16x32_bf16(af[0], bg[n % 3][ni], acc[0][ni], 0, 0, 0);
                acc[1][ni] = __builtin_amdgcn_mfma_f32_16x16x32_bf16(af[1], bg[n % 3][ni], acc[1][ni], 0, 0, 0);
            }
            if (mtc == 3) {
#pragma unroll
                for (int ni = 0; ni < 6; ni++)
                    acc[2][ni] = __builtin_amdgcn_mfma_f32_16x16x32_bf16(af[2], bg[n % 3][ni], acc[2][ni], 0, 0, 0);
            }
            __builtin_amdgcn_s_setprio(0);
        }

        // ---- epilogue: bias + relu (in place) ----
        float bv[6];
#pragma unroll
        for (int ni = 0; ni < 6; ni++) bv[ni] = bp[col0 + ni * 16];
#pragma unroll
        for (int mt = 0; mt < 3; mt++)
            if (mt < mtc)
#pragma unroll
                for (int ni = 0; ni < 6; ni++)
#pragma unroll
                    for (int r = 0; r < 4; r++) {
                        float vv = acc[mt][ni][r] + bv[ni];
                        acc[mt][ni][r] = vv > 0.f ? vv : 0.f;
                    }

        if (st == 1 || st == 3) {
            // ---- LayerNorm: row stats via lx-shuffle + cross-wave LDS reduce ----
#pragma unroll
            for (int mt = 0; mt < 3; mt++)
                if (mt < mtc)
#pragma unroll
                    for (int r = 0; r < 4; r++) {
                        float s1 = 0.f, s2 = 0.f;
#pragma unroll
                        for (int ni = 0; ni < 6; ni++) {
                            s1 += acc[mt][ni][r];
                            s2 += acc[mt][ni][r] * acc[mt][ni][r];
                        }
#pragma unroll
                        for (int d = 1; d < 16; d <<= 1) {
                            s1 += __shfl_xor(s1, d);
                            s2 += __shfl_xor(s2, d);
                        }
                        if (lx == 0) {
                            int beta = (mtb + mt) * 16 + quad * 4 + r + 1;
                            red1[beta * 8 + wave] = s1;
                            red2[beta * 8 + wave] = s2;
                        }
                    }
            __syncthreads();
            if (tid < BROWS) {
                // owner waves of row tid: tiles 0..2 -> w in {0..3}; tiles 3..4 -> {4..7}
                int tile = (tid - 1) >> 4;
                int base = (tile >= 3) ? 4 : 0;
                float s1 = 0.f, s2 = 0.f;
#pragma unroll
                for (int k = 0; k < 4; k++) { s1 += red1[tid * 8 + base + k]; s2 += red2[tid * 8 + base + k]; }
                float mean = s1 * (1.f / D_);
                float var  = s2 * (1.f / D_) - mean * mean;
                minv[tid * 2]     = mean;
                minv[tid * 2 + 1] = rsqrtf(var + 1e-5f);
            }
            __syncthreads();
            const float* gp = (st == 1) ? g1 : g2;
            const float* ep = (st == 1) ? e1 : e2;
            float gv[6], ev[6];
#pragma unroll
            for (int ni = 0; ni < 6; ni++) { gv[ni] = gp[col0 + ni * 16]; ev[ni] = ep[col0 + ni * 16]; }
#pragma unroll
            for (int mt = 0; mt < 3; mt++)
                if (mt < mtc)
#pragma unroll
                    for (int r = 0; r < 4; r++) {
                        int beta = (mtb + mt) * 16 + quad * 4 + r + 1;
                        float mean = minv[beta * 2], inv = minv[beta * 2 + 1];
#pragma unroll
                        for (int ni = 0; ni < 6; ni++)
                            acc[mt][ni][r] = (acc[mt][ni][r] - mean) * inv * gv[ni] + ev[ni];
                    }
            if (st == 1) {
#pragma unroll
                for (int mt = 0; mt < 3; mt++)
                    if (mt < mtc)
#pragma unroll
                        for (int r = 0; r < 4; r++) {
                            int beta = (mtb + mt) * 16 + quad * 4 + r + 1;
                            bool ok = (unsigned)(l0 + beta - 9) < (unsigned)L_;
#pragma unroll
                            for (int ni = 0; ni < 6; ni++)
                                bout[beta * LDW + col0 + ni * 16] = (__bf16)(ok ? acc[mt][ni][r] : 0.f);
                        }
            } else {
                // ---- head: dot with lin_w, cross-wave reduce, store dur_preds ----
                float lwv[6];
#pragma unroll
                for (int ni = 0; ni < 6; ni++) lwv[ni] = lw[col0 + ni * 16];
#pragma unroll
                for (int mt = 0; mt < 3; mt++)
                    if (mt < mtc)
#pragma unroll
                        for (int r = 0; r < 4; r++) {
                            float p = 0.f;
#pragma unroll
                            for (int ni = 0; ni < 6; ni++) p += acc[mt][ni][r] * lwv[ni];
#pragma unroll
                            for (int d = 1; d < 16; d <<= 1) p += __shfl_xor(p, d);
                            if (lx == 0) {
                                int beta = (mtb + mt) * 16 + quad * 4 + r + 1;
                                red1[beta * 8 + wave] = p;
                            }
                        }
                __syncthreads();
                if (tid < 64) {
                    int beta = tid + 9;
                    int tile = (beta - 1) >> 4;
                    int base = (tile >= 3) ? 4 : 0;
                    float sacc = lb[0];
#pragma unroll
                    for (int k = 0; k < 4; k++) sacc += red1[beta * 8 + base + k];
                    out_dur[m0 + tid] = sacc;
                }
            }
        } else {
            // ---- plain write (conv1a / conv2a outputs) ----
#pragma unroll
            for (int mt = 0; mt < 3; mt++)
                if (mt < mtc)
#pragma unroll
                    for (int r = 0; r < 4; r++) {
                        int beta = (mtb + mt) * 16 + quad * 4 + r + 1;
                        bool ok = (unsigned)(l0 + beta - 9) < (unsigned)L_;
#pragma unroll
                        for (int ni = 0; ni < 6; ni++)
                            bout[beta * LDW + col0 + ni * 16] = (__bf16)(ok ? acc[mt][ni][r] : 0.f);
                    }
        }
        __syncthreads();
    }
}

// ---------------- cumsum of durations, wave per batch ----------------
__global__ __launch_bounds__(64) void cum_kernel(const int* __restrict__ dur,
                                                 int* __restrict__ cum)
{
    int b = blockIdx.x, lane = threadIdx.x;
    const int* db = dur + b * L_;
    int v[8], s = 0;
#pragma unroll
    for (int i = 0; i < 8; i++) { v[i] = db[lane * 8 + i]; s += v[i]; }
    int ex = s;
#pragma unroll
    for (int off = 1; off < 64; off <<= 1) {
        int n = __shfl_up(ex, off);
        if (lane >= off) ex += n;
    }
    ex -= s;
    int c = ex;
    int* cb = cum + b * L_;
#pragma unroll
    for (int i = 0; i < 8; i++) { c += v[i]; cb[lane * 8 + i] = c; }
}

// ---------------- scatter / length-regulate (r12): block per PHONEME ------------
// Inverts the old per-frame binary search (9-deep ~1800-cycle dependent L2 chain
// per 1.5 KB moved). Each block (b,l) reads cum[l-1], cum[l] directly, loads its
// x-row once, and writes dur (0..7) contiguous 1.5 KB frames (up to 10.7 KB of
// contiguous stores). Tail frames [total, T) are zeroed by ztail_kernel.
__global__ __launch_bounds__(128) void scatter_kernel(const float* __restrict__ x,
                                                      const int* __restrict__ cum,
                                                      float* __restrict__ out, int T)
{
    int pl = blockIdx.x;              // b*L_ + l
    int b  = pl >> 9;
    int l  = pl & (L_ - 1);
    const int* cb = cum + b * L_;
    int e = cb[l];
    int s = l ? cb[l - 1] : 0;
    if (e == s) return;
    int tid = threadIdx.x;
    float4 v = make_float4(0.f, 0.f, 0.f, 0.f);
    if (tid < 96) v = *(const float4*)(x + (size_t)pl * D_ + tid * 4);
    float* ob = out + ((size_t)b * T) * D_ + tid * 4;
    if (tid < 96)
        for (int t = s; t < e; ++t)
            *(float4*)(ob + (size_t)t * D_) = v;
}

// ---------------- zero-fill tail frames [total_b, T) ------------------------------
__global__ __launch_bounds__(256) void ztail_kernel(const int* __restrict__ cum,
                                                    float* __restrict__ out, int T)
{
    int b = blockIdx.y;
    int total = cum[b * L_ + L_ - 1];
    int nfr = T - total;
    if (nfr <= 0) return;
    float* base = out + ((size_t)b * T + total) * D_;
    int n4 = nfr * 96;                // float4 stores
    for (int i = blockIdx.x * 256 + threadIdx.x; i < n4; i += gridDim.x * 256) {
        int fr = i / 96, q = i - fr * 96;
        *(float4*)(base + (size_t)fr * D_ + q * 4) = make_float4(0.f, 0.f, 0.f, 0.f);
    }
}

extern "C" void kernel_launch(void* const* d_in, const int* in_sizes, int n_in,
                              void* d_out, int out_size, void* d_ws, size_t ws_size,
                              hipStream_t stream) {
    const float* x       = (const float*)d_in[0];
    const int*   dur     = (const int*)d_in[1];
    const float* c1a_w   = (const float*)d_in[2];
    const float* c1a_b   = (const float*)d_in[3];
    const float* c1b_w   = (const float*)d_in[4];
    const float* c1b_b   = (const float*)d_in[5];
    const float* ln1_g   = (const float*)d_in[6];
    const float* ln1_b   = (const float*)d_in[7];
    const float* c2a_w   = (const float*)d_in[8];
    const float* c2a_b   = (const float*)d_in[9];
    const float* c2b_w   = (const float*)d_in[10];
    const float* c2b_b   = (const float*)d_in[11];
    const float* ln2_g   = (const float*)d_in[12];
    const float* ln2_b   = (const float*)d_in[13];
    const float* lin_w   = (const float*)d_in[14];
    const float* lin_b   = (const float*)d_in[15];

    const int T = (out_size - B_ * L_) / (B_ * D_);
    float* out_gather = (float*)d_out;
    float* out_dur    = (float*)d_out + (size_t)B_ * T * D_;

    // workspace: 4 repacked weights + cumsum
    char* p = (char*)d_ws;
    __bf16* w1a = (__bf16*)p; p += (size_t)D_ * KTOT * 2;
    __bf16* w1b = (__bf16*)p; p += (size_t)D_ * KTOT * 2;
    __bf16* w2a = (__bf16*)p; p += (size_t)D_ * KTOT * 2;
    __bf16* w2b = (__bf16*)p; p += (size_t)D_ * KTOT * 2;
    int* cum = (int*)p; p += (size_t)B_ * L_ * 4;

    // LR path (independent of predictor chain)
    cum_kernel<<<B_, 64, 0, stream>>>(dur, cum);
    scatter_kernel<<<B_ * L_, 128, 0, stream>>>(x, cum, out_gather, T);
    ztail_kernel<<<dim3(16, B_), 256, 0, stream>>>(cum, out_gather, T);

    // predictor chain: repack -> one fused kernel
    dim3 rpgrid((D_ * KTOT + 255) / 256, 4);
    repack4_kernel<<<rpgrid, 256, 0, stream>>>(c1a_w, c1b_w, c2a_w, c2b_w, w1a, w1b, w2a, w2b);

    const size_t smem = (size_t)2 * BUFE * 2 + (BROWS * 8 * 2 + BROWS * 2) * 4;  // 134480 B
    static bool attr_set = false;
    if (!attr_set) {
        hipFuncSetAttribute((const void*)fused_predictor,
                            hipFuncAttributeMaxDynamicSharedMemorySize, (int)smem);
        attr_set = true;
    }
    fused_predictor<<<256, 512, smem, stream>>>(
        x, w1a, c1a_b, w1b, c1b_b, ln1_g, ln1_b,
        w2a, c2a_b, w2b, c2b_b, ln2_g, ln2_b,
        lin_w, lin_b, out_dur);
}